// Round 3
// baseline (2333.566 us; speedup 1.0000x reference)
//
#include <hip/hip_runtime.h>
#include <hip/hip_bf16.h>
#include <math.h>

// Problem constants
#define B_  16
#define NE_ 512
#define NIN_ 1024
#define NOUT_ 1024
#define H_ 16
#define HD_ 64
#define ROWS_ (B_ * NE_)          // 8192
#define HHD_ (H_ * HD_)           // 1024

// ---------------------------------------------------------------------------
// LayerNorm (PyTorch-style: unbiased std (ddof=1), eps added to std)
// One block of 256 threads per row of 1024 floats.
// ---------------------------------------------------------------------------
__global__ __launch_bounds__(256) void layernorm_kernel(
    const float* __restrict__ in, const float* __restrict__ alpha,
    const float* __restrict__ beta, float* __restrict__ out) {
  const int row = blockIdx.x;
  const int t = threadIdx.x;
  const float4 v = *reinterpret_cast<const float4*>(&in[(size_t)row * 1024 + t * 4]);
  float s = v.x + v.y + v.z + v.w;
  float ss = v.x * v.x + v.y * v.y + v.z * v.z + v.w * v.w;
  #pragma unroll
  for (int off = 32; off >= 1; off >>= 1) {
    s += __shfl_xor(s, off);
    ss += __shfl_xor(ss, off);
  }
  __shared__ float red[8];
  const int w = t >> 6, lane = t & 63;
  if (lane == 0) { red[w] = s; red[4 + w] = ss; }
  __syncthreads();
  s = red[0] + red[1] + red[2] + red[3];
  ss = red[4] + red[5] + red[6] + red[7];
  const float mean = s * (1.0f / 1024.0f);
  float var = (ss - 1024.0f * mean * mean) * (1.0f / 1023.0f);
  var = fmaxf(var, 0.0f);
  const float inv = 1.0f / (sqrtf(var) + 1e-6f);
  const float4 a = *reinterpret_cast<const float4*>(&alpha[t * 4]);
  const float4 bt = *reinterpret_cast<const float4*>(&beta[t * 4]);
  float4 o;
  o.x = a.x * (v.x - mean) * inv + bt.x;
  o.y = a.y * (v.y - mean) * inv + bt.y;
  o.z = a.z * (v.z - mean) * inv + bt.z;
  o.w = a.w * (v.w - mean) * inv + bt.w;
  *reinterpret_cast<float4*>(&out[(size_t)row * 1024 + t * 4]) = o;
}

// ---------------------------------------------------------------------------
// fp32 NT GEMM: C[M,N] = A[M,K] * W[N,K]^T + bias[N]
// A row-major [M,K], W row-major [N,K] (PyTorch Linear layout).
// 128x128 tile, BK=16, 256 threads, 8x8 micro-tile split as 4+4 with a
// 64-element offset so LDS compute reads are at worst 2-way conflicts (free).
// LDS staged transposed ([k][row]) with stride 132.
// ---------------------------------------------------------------------------
#define BT 128   // tile
#define BKK 16   // k-step
#define LDT 132  // padded LDS stride (floats)

__global__ __launch_bounds__(256) void gemm_nt_bias(
    const float* __restrict__ A, const float* __restrict__ W,
    const float* __restrict__ bias, float* __restrict__ C) {
  __shared__ float As[BKK][LDT];
  __shared__ float Ws[BKK][LDT];
  const int tid = threadIdx.x;
  const int ty = tid >> 4;   // 0..15
  const int tx = tid & 15;   // 0..15
  const int rb = blockIdx.y * BT;
  const int cb = blockIdx.x * BT;
  const int K = 1024, N = 1024;

  float acc[8][8] = {};  // rows {ty*4+i, 64+ty*4+i}, cols {tx*4+j, 64+tx*4+j}

  for (int kt = 0; kt < K; kt += BKK) {
    #pragma unroll
    for (int i = 0; i < 2; ++i) {
      const int L = tid + i * 256;   // 512 float4 slots
      const int row = L >> 2;        // 128 rows, 4 float4 per row
      const int c4 = L & 3;
      const float4 av = *reinterpret_cast<const float4*>(
          &A[(size_t)(rb + row) * K + kt + c4 * 4]);
      As[c4 * 4 + 0][row] = av.x; As[c4 * 4 + 1][row] = av.y;
      As[c4 * 4 + 2][row] = av.z; As[c4 * 4 + 3][row] = av.w;
      const float4 wv = *reinterpret_cast<const float4*>(
          &W[(size_t)(cb + row) * K + kt + c4 * 4]);
      Ws[c4 * 4 + 0][row] = wv.x; Ws[c4 * 4 + 1][row] = wv.y;
      Ws[c4 * 4 + 2][row] = wv.z; Ws[c4 * 4 + 3][row] = wv.w;
    }
    __syncthreads();
    #pragma unroll
    for (int k = 0; k < BKK; ++k) {
      float ar[8], br[8];
      *reinterpret_cast<float4*>(&ar[0]) =
          *reinterpret_cast<const float4*>(&As[k][ty * 4]);
      *reinterpret_cast<float4*>(&ar[4]) =
          *reinterpret_cast<const float4*>(&As[k][64 + ty * 4]);
      *reinterpret_cast<float4*>(&br[0]) =
          *reinterpret_cast<const float4*>(&Ws[k][tx * 4]);
      *reinterpret_cast<float4*>(&br[4]) =
          *reinterpret_cast<const float4*>(&Ws[k][64 + tx * 4]);
      #pragma unroll
      for (int i = 0; i < 8; ++i)
        #pragma unroll
        for (int j = 0; j < 8; ++j)
          acc[i][j] += ar[i] * br[j];
    }
    __syncthreads();
  }

  const float4 bl = *reinterpret_cast<const float4*>(&bias[cb + tx * 4]);
  const float4 bh = *reinterpret_cast<const float4*>(&bias[cb + 64 + tx * 4]);
  #pragma unroll
  for (int i = 0; i < 8; ++i) {
    const int row = rb + (i < 4 ? ty * 4 + i : 64 + ty * 4 + (i - 4));
    float4 o0, o1;
    o0.x = acc[i][0] + bl.x; o0.y = acc[i][1] + bl.y;
    o0.z = acc[i][2] + bl.z; o0.w = acc[i][3] + bl.w;
    o1.x = acc[i][4] + bh.x; o1.y = acc[i][5] + bh.y;
    o1.z = acc[i][6] + bh.z; o1.w = acc[i][7] + bh.w;
    *reinterpret_cast<float4*>(&C[(size_t)row * N + cb + tx * 4]) = o0;
    *reinterpret_cast<float4*>(&C[(size_t)row * N + cb + 64 + tx * 4]) = o1;
  }
}

// ---------------------------------------------------------------------------
// Attention per (b, h, q-tile of 32 rows):
//   phase 1: S = (Q K^T)/8, masked -> LDS scores [32][512]
//   phase 2: wave-parallel softmax, writes e to global + normalized back to LDS
//   phase 3: PV with V staged in LDS, writes concat-layout attention output
// Q/K/V are stored as [B*NE][H*HD] row-major (projection output layout);
// head h occupies columns h*64..h*64+63.
// mask is int32 on device (harness convention: integer -> const int*).
// ---------------------------------------------------------------------------
#define KLD 68   // padded LDS stride for K/V staging
#define SLD 516  // padded score stride (floats)

__global__ __launch_bounds__(256) void attn_kernel(
    const float* __restrict__ Qg, const float* __restrict__ Kg,
    const float* __restrict__ Vg, const int* __restrict__ mask,
    float* __restrict__ e_out, float* __restrict__ attn_out) {
  const int qt = blockIdx.x;   // 0..15
  const int h  = blockIdx.y;   // 0..15
  const int b  = blockIdx.z;   // 0..15
  const int q0 = qt * 32;

  __shared__ float Qs[64][34];    // [d][q]
  __shared__ float Ks[64][KLD];   // [d][k] for phase 1; reused as Vs[k][d] phase 3
  __shared__ float sS[32][SLD];

  const int tid = threadIdx.x;
  const int w = tid >> 6, lane = tid & 63;
  const int ty = tid >> 4, tx = tid & 15;

  // stage Q tile [32 rows][64 d] transposed -> Qs[d][q]
  #pragma unroll
  for (int i = 0; i < 2; ++i) {
    const int L = tid + i * 256;   // 512 float4
    const int q = L >> 4;          // 16 float4 per row
    const int dc = L & 15;
    const float4 v = *reinterpret_cast<const float4*>(
        &Qg[(size_t)(b * NE_ + q0 + q) * HHD_ + h * HD_ + dc * 4]);
    Qs[dc * 4 + 0][q] = v.x; Qs[dc * 4 + 1][q] = v.y;
    Qs[dc * 4 + 2][q] = v.z; Qs[dc * 4 + 3][q] = v.w;
  }

  // ---- phase 1: scores ----
  for (int kt = 0; kt < 8; ++kt) {
    __syncthreads();  // Ks reuse safety (and covers Q staging on kt==0)
    #pragma unroll
    for (int i = 0; i < 4; ++i) {
      const int L = tid + i * 256;   // 1024 float4
      const int kl = L >> 4;
      const int dc = L & 15;
      const float4 v = *reinterpret_cast<const float4*>(
          &Kg[(size_t)(b * NE_ + kt * 64 + kl) * HHD_ + h * HD_ + dc * 4]);
      Ks[dc * 4 + 0][kl] = v.x; Ks[dc * 4 + 1][kl] = v.y;
      Ks[dc * 4 + 2][kl] = v.z; Ks[dc * 4 + 3][kl] = v.w;
    }
    __syncthreads();

    float acc[2][4] = {};
    #pragma unroll
    for (int d = 0; d < 64; ++d) {
      const float2 qv = *reinterpret_cast<const float2*>(&Qs[d][ty * 2]);
      const float4 kv = *reinterpret_cast<const float4*>(&Ks[d][tx * 4]);
      acc[0][0] += qv.x * kv.x; acc[0][1] += qv.x * kv.y;
      acc[0][2] += qv.x * kv.z; acc[0][3] += qv.x * kv.w;
      acc[1][0] += qv.y * kv.x; acc[1][1] += qv.y * kv.y;
      acc[1][2] += qv.y * kv.z; acc[1][3] += qv.y * kv.w;
    }
    #pragma unroll
    for (int i = 0; i < 2; ++i) {
      const int q = ty * 2 + i;
      const int kk = kt * 64 + tx * 4;
      const int4 mv = *reinterpret_cast<const int4*>(
          &mask[(size_t)(b * NE_ + q0 + q) * NE_ + kk]);
      const int mr[4] = {mv.x, mv.y, mv.z, mv.w};
      #pragma unroll
      for (int j = 0; j < 4; ++j) {
        const float sv = acc[i][j] * 0.125f;
        sS[q][kk + j] = mr[j] ? -INFINITY : sv;
      }
    }
  }
  __syncthreads();

  // ---- phase 2: softmax (wave w handles rows w*8..w*8+7) ----
  #pragma unroll
  for (int i = 0; i < 8; ++i) {
    const int r = w * 8 + i;
    float vals[8];
    float m = -INFINITY;
    #pragma unroll
    for (int c = 0; c < 8; ++c) {
      vals[c] = sS[r][lane + 64 * c];
      m = fmaxf(m, vals[c]);
    }
    #pragma unroll
    for (int off = 32; off >= 1; off >>= 1) m = fmaxf(m, __shfl_xor(m, off));
    float sum = 0.0f;
    #pragma unroll
    for (int c = 0; c < 8; ++c) {
      vals[c] = __expf(vals[c] - m);
      sum += vals[c];
    }
    #pragma unroll
    for (int off = 32; off >= 1; off >>= 1) sum += __shfl_xor(sum, off);
    const float inv = 1.0f / sum;
    float* erow = &e_out[(size_t)((b * H_ + h) * NE_ + q0 + r) * NE_];
    #pragma unroll
    for (int c = 0; c < 8; ++c) {
      const float ev = vals[c] * inv;
      sS[r][lane + 64 * c] = ev;
      erow[lane + 64 * c] = ev;
    }
  }

  // ---- phase 3: PV, V staged in LDS (reusing Ks buffer as Vs[k][d]) ----
  float acc8[8] = {};
  for (int kt = 0; kt < 8; ++kt) {
    __syncthreads();
    #pragma unroll
    for (int i = 0; i < 4; ++i) {
      const int L = tid + i * 256;
      const int kl = L >> 4;
      const int dc = L & 15;
      const float4 v = *reinterpret_cast<const float4*>(
          &Vg[(size_t)(b * NE_ + kt * 64 + kl) * HHD_ + h * HD_ + dc * 4]);
      *reinterpret_cast<float4*>(&Ks[kl][dc * 4]) = v;
    }
    __syncthreads();
    #pragma unroll
    for (int k2 = 0; k2 < 64; ++k2) {
      const float v = Ks[k2][lane];
      const int k = kt * 64 + k2;
      #pragma unroll
      for (int i = 0; i < 8; ++i) acc8[i] += sS[w * 8 + i][k] * v;
    }
  }
  #pragma unroll
  for (int i = 0; i < 8; ++i) {
    attn_out[(size_t)(b * NE_ + q0 + w * 8 + i) * HHD_ + h * HD_ + lane] = acc8[i];
  }
}

// ---------------------------------------------------------------------------
extern "C" void kernel_launch(void* const* d_in, const int* in_sizes, int n_in,
                              void* d_out, int out_size, void* d_ws, size_t ws_size,
                              hipStream_t stream) {
  const float* events = (const float*)d_in[0];
  const int* mask = (const int*)d_in[1];            // bool -> int32 on device
  const float* n1a = (const float*)d_in[2];
  const float* n1b = (const float*)d_in[3];
  const float* WQw = (const float*)d_in[4];
  const float* WQb = (const float*)d_in[5];
  const float* WKw = (const float*)d_in[6];
  const float* WKb = (const float*)d_in[7];
  const float* WVw = (const float*)d_in[8];
  const float* WVb = (const float*)d_in[9];
  const float* WOw = (const float*)d_in[10];
  const float* WOb = (const float*)d_in[11];
  const float* n2a = (const float*)d_in[12];
  const float* n2b = (const float*)d_in[13];

  float* out = (float*)d_out;                       // [16,512,1024]
  float* e_out = out + (size_t)ROWS_ * NOUT_;       // [16,16,512,512]

  const size_t MAT = (size_t)ROWS_ * HHD_;          // 8M floats = 32 MB
  float* xn = (float*)d_ws;        // x_norm, later reused as attn concat out
  float* Qb = xn + MAT;            // Q, later reused as WO output
  float* Kb = Qb + MAT;
  float* Vb = Kb + MAT;
  float* attn = xn;
  float* wo_out = Qb;

  // 1) layernorm1
  layernorm_kernel<<<ROWS_, 256, 0, stream>>>(events, n1a, n1b, xn);

  // 2) Q/K/V projections
  dim3 gg(HHD_ / BT, ROWS_ / BT);  // (8, 64)
  gemm_nt_bias<<<gg, 256, 0, stream>>>(xn, WQw, WQb, Qb);
  gemm_nt_bias<<<gg, 256, 0, stream>>>(xn, WKw, WKb, Kb);
  gemm_nt_bias<<<gg, 256, 0, stream>>>(xn, WVw, WVb, Vb);

  // 3) attention (+ e output)
  attn_kernel<<<dim3(NE_ / 32, H_, B_), 256, 0, stream>>>(Qb, Kb, Vb, mask,
                                                          e_out, attn);

  // 4) output projection
  gemm_nt_bias<<<gg, 256, 0, stream>>>(attn, WOw, WOb, wo_out);

  // 5) layernorm2
  layernorm_kernel<<<ROWS_, 256, 0, stream>>>(wo_out, n2a, n2b, out);
}